// Round 6
// baseline (312.585 us; speedup 1.0000x reference)
//
#include <hip/hip_runtime.h>
#include <hip/hip_bf16.h>
#include <cstddef>
#include <cstdint>

#define IN_C 256
#define OUT_C 64
#define NEG_SLOPE 0.2f
#define BKT2 512       // nodes per destination bucket (bucket = c >> 9)
#define PCHUNK 4096    // edges per block in partition kernel
#define MAXB 256       // LDS array size (>= number of buckets = 196)
#define CAP 18432      // fixed record capacity per bucket (mean 16326, +16 sigma)

typedef __attribute__((ext_vector_type(4))) float f32x4;
typedef __attribute__((ext_vector_type(2))) float f32x2;
typedef __attribute__((ext_vector_type(8))) short s16x8;

__device__ __forceinline__ float bf2f(ushort u)
{
    return __uint_as_float(((uint32_t)u) << 16);
}

__device__ __forceinline__ ushort f2bf(float f)
{
    uint32_t u = __float_as_uint(f);
    u += 0x7fffu + ((u >> 16) & 1u);   // round-to-nearest-even
    return (ushort)(u >> 16);
}

// pack two fp32 -> {bf16(f1)<<16 | bf16(f0)}
__device__ __forceinline__ uint32_t pack_bf2(float f0, float f1)
{
    const uint32_t u0 = __float_as_uint(f0) + 0x8000u;
    const uint32_t u1 = __float_as_uint(f1) + 0x8000u;
    return (u1 & 0xffff0000u) | (u0 >> 16);
}

// leaky-relu then exp; branchless max form (t>=0: t >= 0.2t; t<0: 0.2t > t)
__device__ __forceinline__ float lrelu_exp(float t)
{
    return __expf(fmaxf(t, NEG_SLOPE * t));
}

// ---------------------------------------------------------------------------
// W -> bf16 B-fragment order (blocks 0..63); block 64 inits bucket cursors.
// ---------------------------------------------------------------------------
__global__ __launch_bounds__(256) void wconv_kernel(
    const float* __restrict__ W, ushort* __restrict__ wfrag,
    int* __restrict__ cursor, int nb)
{
    if (blockIdx.x == 64) {
        const int i = threadIdx.x;
        if (i < nb) cursor[i] = i * CAP;
        return;
    }
    const int idx = blockIdx.x * 256 + threadIdx.x;
    const int j = idx & 7;
    const int l = (idx >> 3) & 63;
    const int n = (idx >> 9) & 3;
    const int t = idx >> 11;
    const int k   = t * 32 + ((l >> 4) << 3) + j;
    const int col = n * 16 + (l & 15);
    wfrag[idx] = f2bf(W[col * IN_C + k]);
}

// ---------------------------------------------------------------------------
// Kernel 1 (MFMA): h = x @ W^T (bf16 out), s_i = h@a_i, s_j = h@a_j (fp32).
// ---------------------------------------------------------------------------
__global__ __launch_bounds__(256) void fused_h_mfma(
    const float* __restrict__ x, const ushort* __restrict__ wfrag,
    const float* __restrict__ a, ushort* __restrict__ hb,
    float* __restrict__ s_i, float* __restrict__ s_j, int n_nodes)
{
    __shared__ ushort Bs[32 * 64 * 8];   // 32 KB

    const int tid = threadIdx.x;
    for (int i = tid; i < 2048; i += 256)
        ((float4*)Bs)[i] = ((const float4*)wfrag)[i];
    __syncthreads();

    const int lane = tid & 63;
    const int wv   = tid >> 6;
    const int m    = lane & 15;
    const int quad = lane >> 4;

    const int base = blockIdx.x * 64 + wv * 16;
    int row = base + m;
    if (row >= n_nodes) row = n_nodes - 1;   // clamped loads, masked stores

    f32x4 acc0 = {0.f, 0.f, 0.f, 0.f};
    f32x4 acc1 = {0.f, 0.f, 0.f, 0.f};
    f32x4 acc2 = {0.f, 0.f, 0.f, 0.f};
    f32x4 acc3 = {0.f, 0.f, 0.f, 0.f};

    const float* xrow = x + (size_t)row * IN_C + quad * 8;

    #pragma unroll
    for (int t = 0; t < 8; ++t) {
        const float4 xa = *(const float4*)(xrow + t * 32);
        const float4 xb = *(const float4*)(xrow + t * 32 + 4);
        union { s16x8 v; uint32_t u[4]; } af;
        af.u[0] = pack_bf2(xa.x, xa.y);
        af.u[1] = pack_bf2(xa.z, xa.w);
        af.u[2] = pack_bf2(xb.x, xb.y);
        af.u[3] = pack_bf2(xb.z, xb.w);

        const s16x8 b0 = *(const s16x8*)(Bs + ((t * 4 + 0) * 64 + lane) * 8);
        const s16x8 b1 = *(const s16x8*)(Bs + ((t * 4 + 1) * 64 + lane) * 8);
        const s16x8 b2 = *(const s16x8*)(Bs + ((t * 4 + 2) * 64 + lane) * 8);
        const s16x8 b3 = *(const s16x8*)(Bs + ((t * 4 + 3) * 64 + lane) * 8);

        acc0 = __builtin_amdgcn_mfma_f32_16x16x32_bf16(af.v, b0, acc0, 0, 0, 0);
        acc1 = __builtin_amdgcn_mfma_f32_16x16x32_bf16(af.v, b1, acc1, 0, 0, 0);
        acc2 = __builtin_amdgcn_mfma_f32_16x16x32_bf16(af.v, b2, acc2, 0, 0, 0);
        acc3 = __builtin_amdgcn_mfma_f32_16x16x32_bf16(af.v, b3, acc3, 0, 0, 0);
    }

    // epilogue: C/D layout col = lane&15, row = quad*4 + reg
    const int c0 = lane & 15;
    const float ai0 = a[c0],      ai1 = a[c0 + 16], ai2 = a[c0 + 32], ai3 = a[c0 + 48];
    const float aj0 = a[64 + c0], aj1 = a[80 + c0], aj2 = a[96 + c0], aj3 = a[112 + c0];

    #pragma unroll
    for (int r = 0; r < 4; ++r) {
        const int rowr = base + quad * 4 + r;
        float pi = acc0[r] * ai0 + acc1[r] * ai1 + acc2[r] * ai2 + acc3[r] * ai3;
        float pj = acc0[r] * aj0 + acc1[r] * aj1 + acc2[r] * aj2 + acc3[r] * aj3;
        pi += __shfl_xor(pi, 1, 64);  pj += __shfl_xor(pj, 1, 64);
        pi += __shfl_xor(pi, 2, 64);  pj += __shfl_xor(pj, 2, 64);
        pi += __shfl_xor(pi, 4, 64);  pj += __shfl_xor(pj, 4, 64);
        pi += __shfl_xor(pi, 8, 64);  pj += __shfl_xor(pj, 8, 64);
        if (rowr < n_nodes) {
            ushort* hr = hb + (size_t)rowr * OUT_C + c0;
            hr[0]  = f2bf(acc0[r]);
            hr[16] = f2bf(acc1[r]);
            hr[32] = f2bf(acc2[r]);
            hr[48] = f2bf(acc3[r]);
            if (c0 == 0) { s_i[rowr] = pi; s_j[rowr] = pj; }
        }
    }
}

// ---------------------------------------------------------------------------
// Partition into fixed-capacity coarse buckets with LDS reorder.
// Record is 4 B: r<<9 | (c&511).  ex recomputed in gather.
// ei loads nontemporal (read-once stream).
// ---------------------------------------------------------------------------
__global__ __launch_bounds__(256) void partition_kernel(
    const int* __restrict__ ei, int* __restrict__ cursor,
    uint32_t* __restrict__ rec, int n_edges, int nb)
{
    __shared__ int      hist[MAXB];
    __shared__ int      lbase[MAXB];
    __shared__ int      gbase[MAXB];
    __shared__ int      lcur[MAXB];
    __shared__ uint32_t srt[PCHUNK];    // 16 KB staging
    __shared__ uint8_t  bmap[PCHUNK];   // 4 KB bucket ids

    const int tid  = threadIdx.x;
    const int base = blockIdx.x * PCHUNK;
    const int lim  = min(PCHUNK, n_edges - base);

    hist[tid] = 0;
    __syncthreads();

    int rA[PCHUNK / 256], cA[PCHUNK / 256];
    #pragma unroll
    for (int k = 0; k < PCHUNK / 256; ++k) {
        const int i = tid + (k << 8);
        if (i < lim) {
            rA[k] = __builtin_nontemporal_load(ei + base + i);
            cA[k] = __builtin_nontemporal_load(ei + n_edges + base + i);
            atomicAdd(&hist[(uint32_t)cA[k] >> 9], 1);
        }
    }
    __syncthreads();

    // block-local exclusive scan of hist + global reserve (one atomic/bucket)
    const int v = hist[tid];
    lbase[tid] = v;
    __syncthreads();
    for (int off = 1; off < 256; off <<= 1) {
        const int mine  = lbase[tid];
        const int other = (tid >= off) ? lbase[tid - off] : 0;
        __syncthreads();
        lbase[tid] = mine + other;
        __syncthreads();
    }
    const int excl = lbase[tid] - v;
    __syncthreads();
    lbase[tid] = excl;
    lcur[tid]  = excl;
    gbase[tid] = (tid < nb && v > 0) ? atomicAdd(&cursor[tid], v) : 0;
    __syncthreads();

    // scatter into LDS staging in block-sorted order
    #pragma unroll
    for (int k = 0; k < PCHUNK / 256; ++k) {
        const int i = tid + (k << 8);
        if (i < lim) {
            const int r = rA[k];
            const int c = cA[k];
            const int b = (uint32_t)c >> 9;
            const int pos = atomicAdd(&lcur[b], 1);
            srt[pos]  = ((uint32_t)r << 9) | (uint32_t)(c & (BKT2 - 1));
            bmap[pos] = (uint8_t)b;
        }
    }
    __syncthreads();

    // linear flush: piecewise-contiguous coalesced burst
    for (int i = tid; i < lim; i += 256) {
        const int b = bmap[i];
        rec[gbase[b] + (i - lbase[b])] = srt[i];
    }
}

// ---------------------------------------------------------------------------
// Refine: one 1024-thread block per 512-node bucket (fixed-cap layout).
// Stage records in LDS (uint4 vectorized), histogram + scan the 512 node
// slots, then scatter DIRECTLY into the bucket's contiguous global window
// (L2-resident, write-merged) — no dst buffer, no flush phase.
// ---------------------------------------------------------------------------
__global__ __launch_bounds__(1024) void refine_kernel(
    uint32_t* __restrict__ rec, const int* __restrict__ cursor,
    int* __restrict__ nodeoff, int n_nodes, int nb)
{
    __shared__ uint32_t recs[CAP];   // 72 KB staging
    __shared__ int hcnt[BKT2];       // 2 KB
    __shared__ int lcur[BKT2];       // 2 KB
    __shared__ int sscan[BKT2];      // 2 KB

    const int b     = blockIdx.x;
    const int tid   = threadIdx.x;
    const int start = b * CAP;
    const int cnt   = min(cursor[b] - start, CAP);

    if (tid < BKT2) hcnt[tid] = 0;
    __syncthreads();

    // stage + histogram (vectorized main body)
    const int cnt4 = cnt >> 2;
    for (int i = tid; i < cnt4; i += 1024) {
        const uint4 rv4 = ((const uint4*)(rec + start))[i];
        ((uint4*)recs)[i] = rv4;
        atomicAdd(&hcnt[rv4.x & (BKT2 - 1)], 1);
        atomicAdd(&hcnt[rv4.y & (BKT2 - 1)], 1);
        atomicAdd(&hcnt[rv4.z & (BKT2 - 1)], 1);
        atomicAdd(&hcnt[rv4.w & (BKT2 - 1)], 1);
    }
    for (int i = (cnt & ~3) + tid; i < cnt; i += 1024) {
        const uint32_t rv = rec[start + i];
        recs[i] = rv;
        atomicAdd(&hcnt[rv & (BKT2 - 1)], 1);
    }
    __syncthreads();

    // inclusive scan over 512 node counts (first 512 threads active)
    if (tid < BKT2) sscan[tid] = hcnt[tid];
    __syncthreads();
    for (int off = 1; off < BKT2; off <<= 1) {
        int mine = 0, other = 0;
        if (tid < BKT2) {
            mine  = sscan[tid];
            other = (tid >= off) ? sscan[tid - off] : 0;
        }
        __syncthreads();
        if (tid < BKT2) sscan[tid] = mine + other;
        __syncthreads();
    }
    if (tid < BKT2) {
        const int myc  = hcnt[tid];
        const int excl = sscan[tid] - myc;
        lcur[tid] = excl;
        const int g = b * BKT2 + tid;
        if (g < n_nodes) nodeoff[g] = start + excl;
    }
    if (b == nb - 1 && tid == 0) nodeoff[n_nodes] = start + cnt;
    __syncthreads();

    // scatter straight into the global bucket window (L2-resident)
    for (int i = tid; i < cnt; i += 1024) {
        const uint32_t rv = recs[i];
        const int pos = atomicAdd(&lcur[rv & (BKT2 - 1)], 1);
        rec[start + pos] = rv;
    }
}

// ---------------------------------------------------------------------------
// Gather: one wave per destination node, 4 edges in parallel (4 lane-groups
// of 16).  Group g owns edges e+g*4..e+g*4+3 -> each lane's 4 rec loads hit
// one contiguous 16 B segment.  rec loads + out store are NONTEMPORAL so L2
// stays dedicated to hb rows (the only reused data).  float2 accumulators
// -> v_pk_fma_f32.  ex recomputed from s_i/s_j (fp32, same math as stored).
// ---------------------------------------------------------------------------
__global__ __launch_bounds__(256) void gather_kernel(
    const uint32_t* __restrict__ rec, const ushort* __restrict__ hb,
    const float* __restrict__ s_i, const float* __restrict__ s_j,
    const int* __restrict__ nodeoff, const int* __restrict__ cursor,
    float* __restrict__ out, int n_nodes)
{
    int wid = (int)((blockIdx.x * 256u + threadIdx.x) >> 6);
    wid = __builtin_amdgcn_readfirstlane(wid);
    if (wid >= n_nodes) return;
    const int lane = threadIdx.x & 63;
    const int g    = lane >> 4;          // edge slot 0..3
    const int l4   = lane & 15;          // channel group: channels 4*l4..4*l4+3
    const uint32_t loff = (uint32_t)(l4 << 3);   // byte offset within row

    const int o = nodeoff[wid];
    int oe;
    if ((wid & (BKT2 - 1)) == BKT2 - 1) {
        const int b = wid >> 9;
        oe = min(cursor[b], b * CAP + CAP);   // bucket end (fixed-cap layout)
    } else {
        oe = nodeoff[wid + 1];
    }

    const float si = s_i[wid];
    const char* hbB = (const char*)hb;

    f32x2 acc01 = {0.f, 0.f};
    f32x2 acc23 = {0.f, 0.f};
    float dsum = 0.f;

    int e = o;
    for (; e + 16 <= oe; e += 16) {
        uint32_t rv[4];
        #pragma unroll
        for (int q = 0; q < 4; ++q)
            rv[q] = __builtin_nontemporal_load(rec + e + (g << 2) + q);
        float sj[4]; uint32_t off[4];
        #pragma unroll
        for (int q = 0; q < 4; ++q) {
            sj[q]  = s_j[rv[q] >> 9];
            off[q] = ((rv[q] & 0xFFFFFE00u) >> 2) + loff;   // r*128 + l4*8
        }
        uint2 hv[4];
        #pragma unroll
        for (int q = 0; q < 4; ++q) hv[q] = *(const uint2*)(hbB + off[q]);
        #pragma unroll
        for (int q = 0; q < 4; ++q) {
            const float t  = si + sj[q];
            const float ex = __expf(fmaxf(t, NEG_SLOPE * t));
            const f32x2 e2 = {ex, ex};
            f32x2 h01, h23;
            h01[0] = __uint_as_float(hv[q].x << 16);
            h01[1] = __uint_as_float(hv[q].x & 0xffff0000u);
            h23[0] = __uint_as_float(hv[q].y << 16);
            h23[1] = __uint_as_float(hv[q].y & 0xffff0000u);
            acc01 += e2 * h01;
            acc23 += e2 * h23;
            dsum += ex;
        }
    }
    for (; e + 4 <= oe; e += 4) {
        const uint32_t rv = __builtin_nontemporal_load(rec + e + g);
        const float sjv = s_j[rv >> 9];
        const uint32_t off = ((rv & 0xFFFFFE00u) >> 2) + loff;
        const uint2 hv = *(const uint2*)(hbB + off);
        const float t  = si + sjv;
        const float ex = __expf(fmaxf(t, NEG_SLOPE * t));
        const f32x2 e2 = {ex, ex};
        f32x2 h01, h23;
        h01[0] = __uint_as_float(hv.x << 16);
        h01[1] = __uint_as_float(hv.x & 0xffff0000u);
        h23[0] = __uint_as_float(hv.y << 16);
        h23[1] = __uint_as_float(hv.y & 0xffff0000u);
        acc01 += e2 * h01;
        acc23 += e2 * h23;
        dsum += ex;
    }
    if (e < oe) {
        const int m = oe - e;                         // 1..3
        const uint32_t rv = rec[e + (g < m ? g : m - 1)];
        const float sjv = s_j[rv >> 9];
        const uint32_t off = ((rv & 0xFFFFFE00u) >> 2) + loff;
        const uint2 hv = *(const uint2*)(hbB + off);
        const float t  = si + sjv;
        const float ex = (g < m) ? __expf(fmaxf(t, NEG_SLOPE * t)) : 0.f;
        const f32x2 e2 = {ex, ex};
        f32x2 h01, h23;
        h01[0] = __uint_as_float(hv.x << 16);
        h01[1] = __uint_as_float(hv.x & 0xffff0000u);
        h23[0] = __uint_as_float(hv.y << 16);
        h23[1] = __uint_as_float(hv.y & 0xffff0000u);
        acc01 += e2 * h01;
        acc23 += e2 * h23;
        dsum += ex;
    }

    // cross-group reduction (4 groups of 16 lanes)
    #pragma unroll
    for (int k = 0; k < 2; ++k) {
        acc01[k] += __shfl_xor(acc01[k], 16, 64);
        acc01[k] += __shfl_xor(acc01[k], 32, 64);
        acc23[k] += __shfl_xor(acc23[k], 16, 64);
        acc23[k] += __shfl_xor(acc23[k], 32, 64);
    }
    dsum += __shfl_xor(dsum, 16, 64);
    dsum += __shfl_xor(dsum, 32, 64);

    // self loop: row = col = node
    const float t0  = si + s_j[wid];
    const float ex0 = __expf(fmaxf(t0, NEG_SLOPE * t0));
    const uint2 hs = *(const uint2*)(hbB + (size_t)wid * 128 + loff);
    acc01[0] += ex0 * __uint_as_float(hs.x << 16);
    acc01[1] += ex0 * __uint_as_float(hs.x & 0xffff0000u);
    acc23[0] += ex0 * __uint_as_float(hs.y << 16);
    acc23[1] += ex0 * __uint_as_float(hs.y & 0xffff0000u);
    dsum += ex0;

    if (g == 0) {
        f32x4 o4;
        o4[0] = acc01[0] / dsum;
        o4[1] = acc01[1] / dsum;
        o4[2] = acc23[0] / dsum;
        o4[3] = acc23[1] / dsum;
        __builtin_nontemporal_store(o4, (f32x4*)(out + (size_t)wid * OUT_C + (l4 << 2)));
    }
}

extern "C" void kernel_launch(void* const* d_in, const int* in_sizes, int n_in,
                              void* d_out, int out_size, void* d_ws, size_t ws_size,
                              hipStream_t stream)
{
    const float* x  = (const float*)d_in[0];
    const int*   ei = (const int*)d_in[1];
    const float* W  = (const float*)d_in[2];
    const float* a  = (const float*)d_in[3];

    const int N  = in_sizes[0] / IN_C;     // 100000
    const int E  = in_sizes[1] / 2;        // 3200000
    const int NB = (N + BKT2 - 1) / BKT2;  // 196

    float* out = (float*)d_out;

    // workspace carve-up (~29 MB)
    char* ws = (char*)d_ws;
    ushort* hb      = (ushort*)ws;                ws += (size_t)N * OUT_C * 2;  // 12.8 MB
    float*  s_i     = (float*)ws;                 ws += (size_t)N * 4;
    float*  s_j     = (float*)ws;                 ws += (size_t)N * 4;
    int*    cursor  = (int*)ws;                   ws += (size_t)MAXB * 4;
    int*    nodeoff = (int*)ws;                   ws += (size_t)(N + 1) * 4;
    ws = (char*)(((uintptr_t)ws + 15) & ~(uintptr_t)15);
    ushort* wfrag   = (ushort*)ws;                ws += 32 * 64 * 8 * 2;        // 32 KB
    ws = (char*)(((uintptr_t)ws + 15) & ~(uintptr_t)15);
    uint32_t* rec   = (uint32_t*)ws;              // NB * CAP * 4 B = 14.5 MB

    // 1. W fragment conversion + cursor init, then projection (MFMA)
    hipLaunchKernelGGL(wconv_kernel, dim3(65), dim3(256), 0, stream,
                       W, wfrag, cursor, NB);
    hipLaunchKernelGGL(fused_h_mfma, dim3((N + 63) / 64), dim3(256), 0, stream,
                       x, wfrag, a, hb, s_i, s_j, N);

    // 2. partition into fixed-capacity coarse buckets (4 B records)
    const int pblocks = (E + PCHUNK - 1) / PCHUNK;
    hipLaunchKernelGGL(partition_kernel, dim3(pblocks), dim3(256), 0, stream,
                       ei, cursor, rec, E, NB);

    // 3. refine buckets into per-node CSR order (direct L2-window scatter)
    hipLaunchKernelGGL(refine_kernel, dim3(NB), dim3(1024), 0, stream,
                       rec, cursor, nodeoff, N, NB);

    // 4. gather-aggregate (one wave per node, 4 parallel edge slots)
    hipLaunchKernelGGL(gather_kernel, dim3((N + 3) / 4), dim3(256), 0, stream,
                       rec, hb, s_i, s_j, nodeoff, cursor, out, N);
}

// Round 8
// 294.057 us; speedup vs baseline: 1.0630x; 1.0630x over previous
//
#include <hip/hip_runtime.h>
#include <hip/hip_bf16.h>
#include <cstddef>
#include <cstdint>

#define IN_C 256
#define OUT_C 64
#define NEG_SLOPE 0.2f
#define BKT2 512       // nodes per destination bucket (bucket = c >> 9)
#define PCHUNK 4096    // edges per block in partition kernel
#define MAXB 256       // LDS array size (>= number of buckets = 196)
#define CAP 18432      // fixed record capacity per bucket (mean 16326, +16 sigma)

typedef __attribute__((ext_vector_type(4))) float f32x4;
typedef __attribute__((ext_vector_type(2))) float f32x2;
typedef __attribute__((ext_vector_type(8))) short s16x8;

__device__ __forceinline__ float bf2f(ushort u)
{
    return __uint_as_float(((uint32_t)u) << 16);
}

__device__ __forceinline__ ushort f2bf(float f)
{
    uint32_t u = __float_as_uint(f);
    u += 0x7fffu + ((u >> 16) & 1u);   // round-to-nearest-even
    return (ushort)(u >> 16);
}

// pack two fp32 -> {bf16(f1)<<16 | bf16(f0)}
__device__ __forceinline__ uint32_t pack_bf2(float f0, float f1)
{
    const uint32_t u0 = __float_as_uint(f0) + 0x8000u;
    const uint32_t u1 = __float_as_uint(f1) + 0x8000u;
    return (u1 & 0xffff0000u) | (u0 >> 16);
}

// leaky-relu then exp; branchless max form (t>=0: t >= 0.2t; t<0: 0.2t > t)
__device__ __forceinline__ float lrelu_exp(float t)
{
    return __expf(fmaxf(t, NEG_SLOPE * t));
}

// ---------------------------------------------------------------------------
// W -> bf16 B-fragment order (blocks 0..63); block 64 inits bucket cursors.
// ---------------------------------------------------------------------------
__global__ __launch_bounds__(256) void wconv_kernel(
    const float* __restrict__ W, ushort* __restrict__ wfrag,
    int* __restrict__ cursor, int nb)
{
    if (blockIdx.x == 64) {
        const int i = threadIdx.x;
        if (i < nb) cursor[i] = i * CAP;
        return;
    }
    const int idx = blockIdx.x * 256 + threadIdx.x;
    const int j = idx & 7;
    const int l = (idx >> 3) & 63;
    const int n = (idx >> 9) & 3;
    const int t = idx >> 11;
    const int k   = t * 32 + ((l >> 4) << 3) + j;
    const int col = n * 16 + (l & 15);
    wfrag[idx] = f2bf(W[col * IN_C + k]);
}

// ---------------------------------------------------------------------------
// Kernel 1 (MFMA): h = x @ W^T (bf16 out), s_i = h@a_i, s_j = h@a_j (fp32).
// ---------------------------------------------------------------------------
__global__ __launch_bounds__(256) void fused_h_mfma(
    const float* __restrict__ x, const ushort* __restrict__ wfrag,
    const float* __restrict__ a, ushort* __restrict__ hb,
    float* __restrict__ s_i, float* __restrict__ s_j, int n_nodes)
{
    __shared__ ushort Bs[32 * 64 * 8];   // 32 KB

    const int tid = threadIdx.x;
    for (int i = tid; i < 2048; i += 256)
        ((float4*)Bs)[i] = ((const float4*)wfrag)[i];
    __syncthreads();

    const int lane = tid & 63;
    const int wv   = tid >> 6;
    const int m    = lane & 15;
    const int quad = lane >> 4;

    const int base = blockIdx.x * 64 + wv * 16;
    int row = base + m;
    if (row >= n_nodes) row = n_nodes - 1;   // clamped loads, masked stores

    f32x4 acc0 = {0.f, 0.f, 0.f, 0.f};
    f32x4 acc1 = {0.f, 0.f, 0.f, 0.f};
    f32x4 acc2 = {0.f, 0.f, 0.f, 0.f};
    f32x4 acc3 = {0.f, 0.f, 0.f, 0.f};

    const float* xrow = x + (size_t)row * IN_C + quad * 8;

    #pragma unroll
    for (int t = 0; t < 8; ++t) {
        const float4 xa = *(const float4*)(xrow + t * 32);
        const float4 xb = *(const float4*)(xrow + t * 32 + 4);
        union { s16x8 v; uint32_t u[4]; } af;
        af.u[0] = pack_bf2(xa.x, xa.y);
        af.u[1] = pack_bf2(xa.z, xa.w);
        af.u[2] = pack_bf2(xb.x, xb.y);
        af.u[3] = pack_bf2(xb.z, xb.w);

        const s16x8 b0 = *(const s16x8*)(Bs + ((t * 4 + 0) * 64 + lane) * 8);
        const s16x8 b1 = *(const s16x8*)(Bs + ((t * 4 + 1) * 64 + lane) * 8);
        const s16x8 b2 = *(const s16x8*)(Bs + ((t * 4 + 2) * 64 + lane) * 8);
        const s16x8 b3 = *(const s16x8*)(Bs + ((t * 4 + 3) * 64 + lane) * 8);

        acc0 = __builtin_amdgcn_mfma_f32_16x16x32_bf16(af.v, b0, acc0, 0, 0, 0);
        acc1 = __builtin_amdgcn_mfma_f32_16x16x32_bf16(af.v, b1, acc1, 0, 0, 0);
        acc2 = __builtin_amdgcn_mfma_f32_16x16x32_bf16(af.v, b2, acc2, 0, 0, 0);
        acc3 = __builtin_amdgcn_mfma_f32_16x16x32_bf16(af.v, b3, acc3, 0, 0, 0);
    }

    // epilogue: C/D layout col = lane&15, row = quad*4 + reg
    const int c0 = lane & 15;
    const float ai0 = a[c0],      ai1 = a[c0 + 16], ai2 = a[c0 + 32], ai3 = a[c0 + 48];
    const float aj0 = a[64 + c0], aj1 = a[80 + c0], aj2 = a[96 + c0], aj3 = a[112 + c0];

    #pragma unroll
    for (int r = 0; r < 4; ++r) {
        const int rowr = base + quad * 4 + r;
        float pi = acc0[r] * ai0 + acc1[r] * ai1 + acc2[r] * ai2 + acc3[r] * ai3;
        float pj = acc0[r] * aj0 + acc1[r] * aj1 + acc2[r] * aj2 + acc3[r] * aj3;
        pi += __shfl_xor(pi, 1, 64);  pj += __shfl_xor(pj, 1, 64);
        pi += __shfl_xor(pi, 2, 64);  pj += __shfl_xor(pj, 2, 64);
        pi += __shfl_xor(pi, 4, 64);  pj += __shfl_xor(pj, 4, 64);
        pi += __shfl_xor(pi, 8, 64);  pj += __shfl_xor(pj, 8, 64);
        if (rowr < n_nodes) {
            ushort* hr = hb + (size_t)rowr * OUT_C + c0;
            hr[0]  = f2bf(acc0[r]);
            hr[16] = f2bf(acc1[r]);
            hr[32] = f2bf(acc2[r]);
            hr[48] = f2bf(acc3[r]);
            if (c0 == 0) { s_i[rowr] = pi; s_j[rowr] = pj; }
        }
    }
}

// ---------------------------------------------------------------------------
// Partition into fixed-capacity coarse buckets with LDS reorder.
// Record is 4 B: r<<9 | (c&511).  ex recomputed in gather.
// ei loads nontemporal (read-once stream, nothing re-reads it).
// ---------------------------------------------------------------------------
__global__ __launch_bounds__(256) void partition_kernel(
    const int* __restrict__ ei, int* __restrict__ cursor,
    uint32_t* __restrict__ rec, int n_edges, int nb)
{
    __shared__ int      hist[MAXB];
    __shared__ int      lbase[MAXB];
    __shared__ int      gbase[MAXB];
    __shared__ int      lcur[MAXB];
    __shared__ uint32_t srt[PCHUNK];    // 16 KB staging
    __shared__ uint8_t  bmap[PCHUNK];   // 4 KB bucket ids

    const int tid  = threadIdx.x;
    const int base = blockIdx.x * PCHUNK;
    const int lim  = min(PCHUNK, n_edges - base);

    hist[tid] = 0;
    __syncthreads();

    int rA[PCHUNK / 256], cA[PCHUNK / 256];
    #pragma unroll
    for (int k = 0; k < PCHUNK / 256; ++k) {
        const int i = tid + (k << 8);
        if (i < lim) {
            rA[k] = __builtin_nontemporal_load(ei + base + i);
            cA[k] = __builtin_nontemporal_load(ei + n_edges + base + i);
            atomicAdd(&hist[(uint32_t)cA[k] >> 9], 1);
        }
    }
    __syncthreads();

    // block-local exclusive scan of hist + global reserve (one atomic/bucket)
    const int v = hist[tid];
    lbase[tid] = v;
    __syncthreads();
    for (int off = 1; off < 256; off <<= 1) {
        const int mine  = lbase[tid];
        const int other = (tid >= off) ? lbase[tid - off] : 0;
        __syncthreads();
        lbase[tid] = mine + other;
        __syncthreads();
    }
    const int excl = lbase[tid] - v;
    __syncthreads();
    lbase[tid] = excl;
    lcur[tid]  = excl;
    gbase[tid] = (tid < nb && v > 0) ? atomicAdd(&cursor[tid], v) : 0;
    __syncthreads();

    // scatter into LDS staging in block-sorted order
    #pragma unroll
    for (int k = 0; k < PCHUNK / 256; ++k) {
        const int i = tid + (k << 8);
        if (i < lim) {
            const int r = rA[k];
            const int c = cA[k];
            const int b = (uint32_t)c >> 9;
            const int pos = atomicAdd(&lcur[b], 1);
            srt[pos]  = ((uint32_t)r << 9) | (uint32_t)(c & (BKT2 - 1));
            bmap[pos] = (uint8_t)b;
        }
    }
    __syncthreads();

    // linear flush: piecewise-contiguous coalesced burst
    for (int i = tid; i < lim; i += 256) {
        const int b = bmap[i];
        rec[gbase[b] + (i - lbase[b])] = srt[i];
    }
}

// ---------------------------------------------------------------------------
// Refine: one 1024-thread block per 512-node bucket (fixed-cap layout).
// Stage records in LDS (uint4 vectorized), histogram + scan the 512 node
// slots, then scatter DIRECTLY into the bucket's contiguous global window
// (L2-resident, write-merged) — no dst buffer, no flush phase.
// ---------------------------------------------------------------------------
__global__ __launch_bounds__(1024) void refine_kernel(
    uint32_t* __restrict__ rec, const int* __restrict__ cursor,
    int* __restrict__ nodeoff, int n_nodes, int nb)
{
    __shared__ uint32_t recs[CAP];   // 72 KB staging
    __shared__ int hcnt[BKT2];       // 2 KB
    __shared__ int lcur[BKT2];       // 2 KB
    __shared__ int sscan[BKT2];      // 2 KB

    const int b     = blockIdx.x;
    const int tid   = threadIdx.x;
    const int start = b * CAP;
    const int cnt   = min(cursor[b] - start, CAP);

    if (tid < BKT2) hcnt[tid] = 0;
    __syncthreads();

    // stage + histogram (vectorized main body)
    const int cnt4 = cnt >> 2;
    for (int i = tid; i < cnt4; i += 1024) {
        const uint4 rv4 = ((const uint4*)(rec + start))[i];
        ((uint4*)recs)[i] = rv4;
        atomicAdd(&hcnt[rv4.x & (BKT2 - 1)], 1);
        atomicAdd(&hcnt[rv4.y & (BKT2 - 1)], 1);
        atomicAdd(&hcnt[rv4.z & (BKT2 - 1)], 1);
        atomicAdd(&hcnt[rv4.w & (BKT2 - 1)], 1);
    }
    for (int i = (cnt & ~3) + tid; i < cnt; i += 1024) {
        const uint32_t rv = rec[start + i];
        recs[i] = rv;
        atomicAdd(&hcnt[rv & (BKT2 - 1)], 1);
    }
    __syncthreads();

    // inclusive scan over 512 node counts (first 512 threads active)
    if (tid < BKT2) sscan[tid] = hcnt[tid];
    __syncthreads();
    for (int off = 1; off < BKT2; off <<= 1) {
        int mine = 0, other = 0;
        if (tid < BKT2) {
            mine  = sscan[tid];
            other = (tid >= off) ? sscan[tid - off] : 0;
        }
        __syncthreads();
        if (tid < BKT2) sscan[tid] = mine + other;
        __syncthreads();
    }
    if (tid < BKT2) {
        const int myc  = hcnt[tid];
        const int excl = sscan[tid] - myc;
        lcur[tid] = excl;
        const int g = b * BKT2 + tid;
        if (g < n_nodes) nodeoff[g] = start + excl;
    }
    if (b == nb - 1 && tid == 0) nodeoff[n_nodes] = start + cnt;
    __syncthreads();

    // scatter straight into the global bucket window (L2-resident)
    for (int i = tid; i < cnt; i += 1024) {
        const uint32_t rv = recs[i];
        const int pos = atomicAdd(&lcur[rv & (BKT2 - 1)], 1);
        rec[start + pos] = rv;
    }
}

// ---------------------------------------------------------------------------
// Gather: one wave per destination node, 8 edges in parallel (8 lane-groups
// of 8).  Each lane loads 16 B (uint4 = 8 bf16 channels) of its group's
// source row -> one hv instruction covers 8 edges (1 KB).  Main iter = 32
// edges: 4 rec + 4 sj + 4 hv VMEM instrs, 8 independent scattered loads in
// flight.  exp covers 8 edges per instruction.  rec loads are PLAIN (the
// array is L2-resident from refine — NT here cost +11 µs in round 6).
// NT kept only on the write-once out store.  Reduction: shfl_xor 8/16/32.
// ---------------------------------------------------------------------------
__global__ __launch_bounds__(256) void gather_kernel(
    const uint32_t* __restrict__ rec, const ushort* __restrict__ hb,
    const float* __restrict__ s_i, const float* __restrict__ s_j,
    const int* __restrict__ nodeoff, const int* __restrict__ cursor,
    float* __restrict__ out, int n_nodes)
{
    int wid = (int)((blockIdx.x * 256u + threadIdx.x) >> 6);
    wid = __builtin_amdgcn_readfirstlane(wid);
    if (wid >= n_nodes) return;
    const int lane = threadIdx.x & 63;
    const int g    = lane >> 3;          // edge slot 0..7
    const int l8   = lane & 7;           // channel block: channels 8*l8..8*l8+7
    const uint32_t loff = (uint32_t)(l8 << 4);   // byte offset within 128 B row

    const int o = nodeoff[wid];
    int oe;
    if ((wid & (BKT2 - 1)) == BKT2 - 1) {
        const int b = wid >> 9;
        oe = min(cursor[b], b * CAP + CAP);   // bucket end (fixed-cap layout)
    } else {
        oe = nodeoff[wid + 1];
    }

    const float si = s_i[wid];
    const char* hbB = (const char*)hb;

    f32x2 a01 = {0.f, 0.f}, a23 = {0.f, 0.f};
    f32x2 a45 = {0.f, 0.f}, a67 = {0.f, 0.f};
    float dsum = 0.f;

    int e = o;
    // main: 32 edges per iter (4 per group-slot)
    for (; e + 32 <= oe; e += 32) {
        uint32_t rv[4];
        #pragma unroll
        for (int q = 0; q < 4; ++q) rv[q] = rec[e + q * 8 + g];
        float sj[4]; uint32_t off[4];
        #pragma unroll
        for (int q = 0; q < 4; ++q) {
            sj[q]  = s_j[rv[q] >> 9];
            off[q] = ((rv[q] & 0xFFFFFE00u) >> 2) + loff;   // r*128 + l8*16
        }
        uint4 hv[4];
        #pragma unroll
        for (int q = 0; q < 4; ++q) hv[q] = *(const uint4*)(hbB + off[q]);
        #pragma unroll
        for (int q = 0; q < 4; ++q) {
            const float t  = si + sj[q];
            const float ex = __expf(fmaxf(t, NEG_SLOPE * t));
            const f32x2 e2 = {ex, ex};
            f32x2 h;
            h[0] = __uint_as_float(hv[q].x << 16);
            h[1] = __uint_as_float(hv[q].x & 0xffff0000u);
            a01 += e2 * h;
            h[0] = __uint_as_float(hv[q].y << 16);
            h[1] = __uint_as_float(hv[q].y & 0xffff0000u);
            a23 += e2 * h;
            h[0] = __uint_as_float(hv[q].z << 16);
            h[1] = __uint_as_float(hv[q].z & 0xffff0000u);
            a45 += e2 * h;
            h[0] = __uint_as_float(hv[q].w << 16);
            h[1] = __uint_as_float(hv[q].w & 0xffff0000u);
            a67 += e2 * h;
            dsum += ex;
        }
    }
    // 8-edge tail blocks
    for (; e + 8 <= oe; e += 8) {
        const uint32_t rv = rec[e + g];
        const float sjv = s_j[rv >> 9];
        const uint32_t off = ((rv & 0xFFFFFE00u) >> 2) + loff;
        const uint4 hv = *(const uint4*)(hbB + off);
        const float t  = si + sjv;
        const float ex = __expf(fmaxf(t, NEG_SLOPE * t));
        const f32x2 e2 = {ex, ex};
        f32x2 h;
        h[0] = __uint_as_float(hv.x << 16);
        h[1] = __uint_as_float(hv.x & 0xffff0000u);
        a01 += e2 * h;
        h[0] = __uint_as_float(hv.y << 16);
        h[1] = __uint_as_float(hv.y & 0xffff0000u);
        a23 += e2 * h;
        h[0] = __uint_as_float(hv.z << 16);
        h[1] = __uint_as_float(hv.z & 0xffff0000u);
        a45 += e2 * h;
        h[0] = __uint_as_float(hv.w << 16);
        h[1] = __uint_as_float(hv.w & 0xffff0000u);
        a67 += e2 * h;
        dsum += ex;
    }
    // remainder 1..7: groups >= m replicate last record with ex = 0
    if (e < oe) {
        const int m = oe - e;
        const uint32_t rv = rec[e + (g < m ? g : m - 1)];
        const float sjv = s_j[rv >> 9];
        const uint32_t off = ((rv & 0xFFFFFE00u) >> 2) + loff;
        const uint4 hv = *(const uint4*)(hbB + off);
        const float t  = si + sjv;
        const float ex = (g < m) ? __expf(fmaxf(t, NEG_SLOPE * t)) : 0.f;
        const f32x2 e2 = {ex, ex};
        f32x2 h;
        h[0] = __uint_as_float(hv.x << 16);
        h[1] = __uint_as_float(hv.x & 0xffff0000u);
        a01 += e2 * h;
        h[0] = __uint_as_float(hv.y << 16);
        h[1] = __uint_as_float(hv.y & 0xffff0000u);
        a23 += e2 * h;
        h[0] = __uint_as_float(hv.z << 16);
        h[1] = __uint_as_float(hv.z & 0xffff0000u);
        a45 += e2 * h;
        h[0] = __uint_as_float(hv.w << 16);
        h[1] = __uint_as_float(hv.w & 0xffff0000u);
        a67 += e2 * h;
        dsum += ex;
    }

    // cross-group reduction over the 8 edge slots (l8 preserved)
    #pragma unroll
    for (int s = 8; s <= 32; s <<= 1) {
        a01[0] += __shfl_xor(a01[0], s, 64);
        a01[1] += __shfl_xor(a01[1], s, 64);
        a23[0] += __shfl_xor(a23[0], s, 64);
        a23[1] += __shfl_xor(a23[1], s, 64);
        a45[0] += __shfl_xor(a45[0], s, 64);
        a45[1] += __shfl_xor(a45[1], s, 64);
        a67[0] += __shfl_xor(a67[0], s, 64);
        a67[1] += __shfl_xor(a67[1], s, 64);
        dsum   += __shfl_xor(dsum,   s, 64);
    }

    // self loop: row = col = node
    const float t0  = si + s_j[wid];
    const float ex0 = __expf(fmaxf(t0, NEG_SLOPE * t0));
    const uint4 hs = *(const uint4*)(hbB + (size_t)wid * 128 + loff);
    a01[0] += ex0 * __uint_as_float(hs.x << 16);
    a01[1] += ex0 * __uint_as_float(hs.x & 0xffff0000u);
    a23[0] += ex0 * __uint_as_float(hs.y << 16);
    a23[1] += ex0 * __uint_as_float(hs.y & 0xffff0000u);
    a45[0] += ex0 * __uint_as_float(hs.z << 16);
    a45[1] += ex0 * __uint_as_float(hs.z & 0xffff0000u);
    a67[0] += ex0 * __uint_as_float(hs.w << 16);
    a67[1] += ex0 * __uint_as_float(hs.w & 0xffff0000u);
    dsum += ex0;

    if (g == 0) {
        const float inv = 1.0f / dsum;
        f32x4 o4;
        o4[0] = a01[0] * inv;
        o4[1] = a01[1] * inv;
        o4[2] = a23[0] * inv;
        o4[3] = a23[1] * inv;
        float* op = out + (size_t)wid * OUT_C + (l8 << 3);
        __builtin_nontemporal_store(o4, (f32x4*)op);
        o4[0] = a45[0] * inv;
        o4[1] = a45[1] * inv;
        o4[2] = a67[0] * inv;
        o4[3] = a67[1] * inv;
        __builtin_nontemporal_store(o4, (f32x4*)(op + 4));
    }
}

extern "C" void kernel_launch(void* const* d_in, const int* in_sizes, int n_in,
                              void* d_out, int out_size, void* d_ws, size_t ws_size,
                              hipStream_t stream)
{
    const float* x  = (const float*)d_in[0];
    const int*   ei = (const int*)d_in[1];
    const float* W  = (const float*)d_in[2];
    const float* a  = (const float*)d_in[3];

    const int N  = in_sizes[0] / IN_C;     // 100000
    const int E  = in_sizes[1] / 2;        // 3200000
    const int NB = (N + BKT2 - 1) / BKT2;  // 196

    float* out = (float*)d_out;

    // workspace carve-up (~29 MB)
    char* ws = (char*)d_ws;
    ushort* hb      = (ushort*)ws;                ws += (size_t)N * OUT_C * 2;  // 12.8 MB
    float*  s_i     = (float*)ws;                 ws += (size_t)N * 4;
    float*  s_j     = (float*)ws;                 ws += (size_t)N * 4;
    int*    cursor  = (int*)ws;                   ws += (size_t)MAXB * 4;
    int*    nodeoff = (int*)ws;                   ws += (size_t)(N + 1) * 4;
    ws = (char*)(((uintptr_t)ws + 15) & ~(uintptr_t)15);
    ushort* wfrag   = (ushort*)ws;                ws += 32 * 64 * 8 * 2;        // 32 KB
    ws = (char*)(((uintptr_t)ws + 15) & ~(uintptr_t)15);
    uint32_t* rec   = (uint32_t*)ws;              // NB * CAP * 4 B = 14.5 MB

    // 1. W fragment conversion + cursor init, then projection (MFMA)
    hipLaunchKernelGGL(wconv_kernel, dim3(65), dim3(256), 0, stream,
                       W, wfrag, cursor, NB);
    hipLaunchKernelGGL(fused_h_mfma, dim3((N + 63) / 64), dim3(256), 0, stream,
                       x, wfrag, a, hb, s_i, s_j, N);

    // 2. partition into fixed-capacity coarse buckets (4 B records)
    const int pblocks = (E + PCHUNK - 1) / PCHUNK;
    hipLaunchKernelGGL(partition_kernel, dim3(pblocks), dim3(256), 0, stream,
                       ei, cursor, rec, E, NB);

    // 3. refine buckets into per-node CSR order (direct L2-window scatter)
    hipLaunchKernelGGL(refine_kernel, dim3(NB), dim3(1024), 0, stream,
                       rec, cursor, nodeoff, N, NB);

    // 4. gather-aggregate (one wave per node, 8 parallel edge slots)
    hipLaunchKernelGGL(gather_kernel, dim3((N + 3) / 4), dim3(256), 0, stream,
                       rec, hb, s_i, s_j, nodeoff, cursor, out, N);
}

// Round 11
// 280.150 us; speedup vs baseline: 1.1158x; 1.0496x over previous
//
#include <hip/hip_runtime.h>
#include <hip/hip_bf16.h>
#include <cstddef>
#include <cstdint>

#define IN_C 256
#define OUT_C 64
#define NEG_SLOPE 0.2f
#define BKT2 256       // nodes per destination bucket (bucket = c >> 8)
#define PCHUNK 4096    // edges per block in partition kernel
#define MAXB 512       // LDS array size (>= number of buckets = 391)
#define CAP 9728       // fixed record capacity per bucket (mean 8163, +17 sigma)

typedef __attribute__((ext_vector_type(4))) float f32x4;
typedef __attribute__((ext_vector_type(2))) float f32x2;
typedef __attribute__((ext_vector_type(8))) short s16x8;

__device__ __forceinline__ ushort f2bf(float f)
{
    uint32_t u = __float_as_uint(f);
    u += 0x7fffu + ((u >> 16) & 1u);   // round-to-nearest-even
    return (ushort)(u >> 16);
}

// pack two fp32 -> {bf16(f1)<<16 | bf16(f0)}
__device__ __forceinline__ uint32_t pack_bf2(float f0, float f1)
{
    const uint32_t u0 = __float_as_uint(f0) + 0x8000u;
    const uint32_t u1 = __float_as_uint(f1) + 0x8000u;
    return (u1 & 0xffff0000u) | (u0 >> 16);
}

// ---------------------------------------------------------------------------
// W -> bf16 B-fragment order (blocks 0..63); block 64 inits bucket cursors.
// ---------------------------------------------------------------------------
__global__ __launch_bounds__(256) void wconv_kernel(
    const float* __restrict__ W, ushort* __restrict__ wfrag,
    int* __restrict__ cursor, int nb)
{
    if (blockIdx.x == 64) {
        for (int i = threadIdx.x; i < nb; i += 256) cursor[i] = i * CAP;
        return;
    }
    const int idx = blockIdx.x * 256 + threadIdx.x;
    const int j = idx & 7;
    const int l = (idx >> 3) & 63;
    const int n = (idx >> 9) & 3;
    const int t = idx >> 11;
    const int k   = t * 32 + ((l >> 4) << 3) + j;
    const int col = n * 16 + (l & 15);
    wfrag[idx] = f2bf(W[col * IN_C + k]);
}

// ---------------------------------------------------------------------------
// Kernel 1 (MFMA): h = x @ W^T (bf16 out), s_i = h@a_i, s_j = h@a_j (fp32).
// ---------------------------------------------------------------------------
__global__ __launch_bounds__(256) void fused_h_mfma(
    const float* __restrict__ x, const ushort* __restrict__ wfrag,
    const float* __restrict__ a, ushort* __restrict__ hb,
    float* __restrict__ s_i, float* __restrict__ s_j, int n_nodes)
{
    __shared__ ushort Bs[32 * 64 * 8];   // 32 KB

    const int tid = threadIdx.x;
    for (int i = tid; i < 2048; i += 256)
        ((float4*)Bs)[i] = ((const float4*)wfrag)[i];
    __syncthreads();

    const int lane = tid & 63;
    const int wv   = tid >> 6;
    const int m    = lane & 15;
    const int quad = lane >> 4;

    const int base = blockIdx.x * 64 + wv * 16;
    int row = base + m;
    if (row >= n_nodes) row = n_nodes - 1;   // clamped loads, masked stores

    f32x4 acc0 = {0.f, 0.f, 0.f, 0.f};
    f32x4 acc1 = {0.f, 0.f, 0.f, 0.f};
    f32x4 acc2 = {0.f, 0.f, 0.f, 0.f};
    f32x4 acc3 = {0.f, 0.f, 0.f, 0.f};

    const float* xrow = x + (size_t)row * IN_C + quad * 8;

    #pragma unroll
    for (int t = 0; t < 8; ++t) {
        const float4 xa = *(const float4*)(xrow + t * 32);
        const float4 xb = *(const float4*)(xrow + t * 32 + 4);
        union { s16x8 v; uint32_t u[4]; } af;
        af.u[0] = pack_bf2(xa.x, xa.y);
        af.u[1] = pack_bf2(xa.z, xa.w);
        af.u[2] = pack_bf2(xb.x, xb.y);
        af.u[3] = pack_bf2(xb.z, xb.w);

        const s16x8 b0 = *(const s16x8*)(Bs + ((t * 4 + 0) * 64 + lane) * 8);
        const s16x8 b1 = *(const s16x8*)(Bs + ((t * 4 + 1) * 64 + lane) * 8);
        const s16x8 b2 = *(const s16x8*)(Bs + ((t * 4 + 2) * 64 + lane) * 8);
        const s16x8 b3 = *(const s16x8*)(Bs + ((t * 4 + 3) * 64 + lane) * 8);

        acc0 = __builtin_amdgcn_mfma_f32_16x16x32_bf16(af.v, b0, acc0, 0, 0, 0);
        acc1 = __builtin_amdgcn_mfma_f32_16x16x32_bf16(af.v, b1, acc1, 0, 0, 0);
        acc2 = __builtin_amdgcn_mfma_f32_16x16x32_bf16(af.v, b2, acc2, 0, 0, 0);
        acc3 = __builtin_amdgcn_mfma_f32_16x16x32_bf16(af.v, b3, acc3, 0, 0, 0);
    }

    // epilogue: C/D layout col = lane&15, row = quad*4 + reg
    const int c0 = lane & 15;
    const float ai0 = a[c0],      ai1 = a[c0 + 16], ai2 = a[c0 + 32], ai3 = a[c0 + 48];
    const float aj0 = a[64 + c0], aj1 = a[80 + c0], aj2 = a[96 + c0], aj3 = a[112 + c0];

    #pragma unroll
    for (int r = 0; r < 4; ++r) {
        const int rowr = base + quad * 4 + r;
        float pi = acc0[r] * ai0 + acc1[r] * ai1 + acc2[r] * ai2 + acc3[r] * ai3;
        float pj = acc0[r] * aj0 + acc1[r] * aj1 + acc2[r] * aj2 + acc3[r] * aj3;
        pi += __shfl_xor(pi, 1, 64);  pj += __shfl_xor(pj, 1, 64);
        pi += __shfl_xor(pi, 2, 64);  pj += __shfl_xor(pj, 2, 64);
        pi += __shfl_xor(pi, 4, 64);  pj += __shfl_xor(pj, 4, 64);
        pi += __shfl_xor(pi, 8, 64);  pj += __shfl_xor(pj, 8, 64);
        if (rowr < n_nodes) {
            ushort* hr = hb + (size_t)rowr * OUT_C + c0;
            hr[0]  = f2bf(acc0[r]);
            hr[16] = f2bf(acc1[r]);
            hr[32] = f2bf(acc2[r]);
            hr[48] = f2bf(acc3[r]);
            if (c0 == 0) { s_i[rowr] = pi; s_j[rowr] = pj; }
        }
    }
}

// ---------------------------------------------------------------------------
// Partition into fixed-capacity coarse buckets with LDS reorder.
// 512 threads; 391 buckets of 256 nodes.  Record = r<<8 | (c&255).
// ei loads nontemporal (read-once stream).
// ---------------------------------------------------------------------------
__global__ __launch_bounds__(512) void partition_kernel(
    const int* __restrict__ ei, int* __restrict__ cursor,
    uint32_t* __restrict__ rec, int n_edges, int nb)
{
    __shared__ int      hist[MAXB];
    __shared__ int      lbase[MAXB];
    __shared__ int      gbase[MAXB];
    __shared__ int      lcur[MAXB];
    __shared__ uint32_t srt[PCHUNK];     // 16 KB staging
    __shared__ uint16_t bmap[PCHUNK];    // 8 KB bucket ids

    const int tid  = threadIdx.x;
    const int base = blockIdx.x * PCHUNK;
    const int lim  = min(PCHUNK, n_edges - base);

    hist[tid] = 0;
    __syncthreads();

    int rA[PCHUNK / 512], cA[PCHUNK / 512];
    #pragma unroll
    for (int k = 0; k < PCHUNK / 512; ++k) {
        const int i = tid + (k << 9);
        if (i < lim) {
            rA[k] = __builtin_nontemporal_load(ei + base + i);
            cA[k] = __builtin_nontemporal_load(ei + n_edges + base + i);
            atomicAdd(&hist[(uint32_t)cA[k] >> 8], 1);
        }
    }
    __syncthreads();

    // block-local exclusive scan of hist + global reserve (one atomic/bucket)
    const int v = hist[tid];
    lbase[tid] = v;
    __syncthreads();
    for (int off = 1; off < 512; off <<= 1) {
        const int mine  = lbase[tid];
        const int other = (tid >= off) ? lbase[tid - off] : 0;
        __syncthreads();
        lbase[tid] = mine + other;
        __syncthreads();
    }
    const int excl = lbase[tid] - v;
    __syncthreads();
    lbase[tid] = excl;
    lcur[tid]  = excl;
    gbase[tid] = (tid < nb && v > 0) ? atomicAdd(&cursor[tid], v) : 0;
    __syncthreads();

    // scatter into LDS staging in block-sorted order
    #pragma unroll
    for (int k = 0; k < PCHUNK / 512; ++k) {
        const int i = tid + (k << 9);
        if (i < lim) {
            const int r = rA[k];
            const int c = cA[k];
            const int b = (uint32_t)c >> 8;
            const int pos = atomicAdd(&lcur[b], 1);
            srt[pos]  = ((uint32_t)r << 8) | (uint32_t)(c & (BKT2 - 1));
            bmap[pos] = (uint16_t)b;
        }
    }
    __syncthreads();

    // linear flush: piecewise-contiguous coalesced burst
    for (int i = tid; i < lim; i += 512) {
        const int b = bmap[i];
        rec[gbase[b] + (i - lbase[b])] = srt[i];
    }
}

// ---------------------------------------------------------------------------
// Fused sort+gather: one 1024-thread block per 256-node bucket.
// Phase 1: histogram bucket records (global read, L2-hot from partition).
// Phase 2: scan 256 node counts -> per-node LDS offsets.
// Phase 3: scatter records into LDS srt[] in per-node CSR order.
// Phase 4: per-node gather exactly as the proven gather kernel, but record
// reads come from LDS (broadcast within 8-lane group, conflict-free).
// 8 lane-groups of 8; each lane loads 16 B (8 bf16 ch) of the source row.
// Eliminates the refine dispatch, the rec rewrite, and nodeoff entirely.
// ---------------------------------------------------------------------------
__global__ __launch_bounds__(1024) void sortgather_kernel(
    const uint32_t* __restrict__ rec, const ushort* __restrict__ hb,
    const float* __restrict__ s_i, const float* __restrict__ s_j,
    const int* __restrict__ cursor, float* __restrict__ out, int n_nodes)
{
    __shared__ uint32_t srt[CAP];        // 38 KB sorted records
    __shared__ int hcnt[BKT2];           // 1 KB
    __shared__ int nstart[BKT2 + 1];     // 1 KB
    __shared__ int lcur[BKT2];           // 1 KB
    __shared__ int sscan[BKT2];          // 1 KB

    const int b     = blockIdx.x;
    const int tid   = threadIdx.x;
    const int start = b * CAP;
    const int cnt   = min(cursor[b] - start, CAP);

    if (tid < BKT2) hcnt[tid] = 0;
    __syncthreads();

    // phase 1: histogram (vectorized global read; rec is L2-resident)
    const int cnt4 = cnt >> 2;
    for (int i = tid; i < cnt4; i += 1024) {
        const uint4 rv4 = ((const uint4*)(rec + start))[i];
        atomicAdd(&hcnt[rv4.x & (BKT2 - 1)], 1);
        atomicAdd(&hcnt[rv4.y & (BKT2 - 1)], 1);
        atomicAdd(&hcnt[rv4.z & (BKT2 - 1)], 1);
        atomicAdd(&hcnt[rv4.w & (BKT2 - 1)], 1);
    }
    for (int i = (cnt & ~3) + tid; i < cnt; i += 1024)
        atomicAdd(&hcnt[rec[start + i] & (BKT2 - 1)], 1);
    __syncthreads();

    // phase 2: inclusive scan over 256 node counts
    if (tid < BKT2) sscan[tid] = hcnt[tid];
    __syncthreads();
    for (int off = 1; off < BKT2; off <<= 1) {
        int mine = 0, other = 0;
        if (tid < BKT2) {
            mine  = sscan[tid];
            other = (tid >= off) ? sscan[tid - off] : 0;
        }
        __syncthreads();
        if (tid < BKT2) sscan[tid] = mine + other;
        __syncthreads();
    }
    if (tid < BKT2) {
        const int excl = sscan[tid] - hcnt[tid];
        nstart[tid] = excl;
        lcur[tid]   = excl;
    }
    if (tid == 0) nstart[BKT2] = cnt;
    __syncthreads();

    // phase 3: scatter into per-node CSR order inside LDS
    for (int i = tid; i < cnt; i += 1024) {
        const uint32_t rv = rec[start + i];
        srt[atomicAdd(&lcur[rv & (BKT2 - 1)], 1)] = rv;
    }
    __syncthreads();

    // phase 4: per-node gather (16 nodes per wave, records from LDS)
    const int lane = tid & 63;
    const int wv   = tid >> 6;
    const int g    = lane >> 3;          // edge slot 0..7
    const int l8   = lane & 7;           // channel block
    const uint32_t loff = (uint32_t)(l8 << 4);
    const char* hbB = (const char*)hb;

    for (int k = 0; k < BKT2 / 16; ++k) {
        const int nl   = wv * (BKT2 / 16) + k;
        const int node = b * BKT2 + nl;
        if (node >= n_nodes) break;
        const int o  = nstart[nl];
        const int oe = nstart[nl + 1];
        const float si = s_i[node];

        f32x2 a01 = {0.f, 0.f}, a23 = {0.f, 0.f};
        f32x2 a45 = {0.f, 0.f}, a67 = {0.f, 0.f};
        float dsum = 0.f;

        int e = o;
        for (; e + 32 <= oe; e += 32) {
            uint32_t rv[4];
            #pragma unroll
            for (int q = 0; q < 4; ++q) rv[q] = srt[e + q * 8 + g];
            float sj[4]; uint32_t off[4];
            #pragma unroll
            for (int q = 0; q < 4; ++q) {
                sj[q]  = s_j[rv[q] >> 8];
                off[q] = ((rv[q] & 0xFFFFFF00u) >> 1) + loff;   // r*128 + l8*16
            }
            uint4 hv[4];
            #pragma unroll
            for (int q = 0; q < 4; ++q) hv[q] = *(const uint4*)(hbB + off[q]);
            #pragma unroll
            for (int q = 0; q < 4; ++q) {
                const float t  = si + sj[q];
                const float ex = __expf(fmaxf(t, NEG_SLOPE * t));
                const f32x2 e2 = {ex, ex};
                f32x2 h;
                h[0] = __uint_as_float(hv[q].x << 16);
                h[1] = __uint_as_float(hv[q].x & 0xffff0000u);
                a01 += e2 * h;
                h[0] = __uint_as_float(hv[q].y << 16);
                h[1] = __uint_as_float(hv[q].y & 0xffff0000u);
                a23 += e2 * h;
                h[0] = __uint_as_float(hv[q].z << 16);
                h[1] = __uint_as_float(hv[q].z & 0xffff0000u);
                a45 += e2 * h;
                h[0] = __uint_as_float(hv[q].w << 16);
                h[1] = __uint_as_float(hv[q].w & 0xffff0000u);
                a67 += e2 * h;
                dsum += ex;
            }
        }
        for (; e + 8 <= oe; e += 8) {
            const uint32_t rv = srt[e + g];
            const float sjv = s_j[rv >> 8];
            const uint32_t off = ((rv & 0xFFFFFF00u) >> 1) + loff;
            const uint4 hv = *(const uint4*)(hbB + off);
            const float t  = si + sjv;
            const float ex = __expf(fmaxf(t, NEG_SLOPE * t));
            const f32x2 e2 = {ex, ex};
            f32x2 h;
            h[0] = __uint_as_float(hv.x << 16);
            h[1] = __uint_as_float(hv.x & 0xffff0000u);
            a01 += e2 * h;
            h[0] = __uint_as_float(hv.y << 16);
            h[1] = __uint_as_float(hv.y & 0xffff0000u);
            a23 += e2 * h;
            h[0] = __uint_as_float(hv.z << 16);
            h[1] = __uint_as_float(hv.z & 0xffff0000u);
            a45 += e2 * h;
            h[0] = __uint_as_float(hv.w << 16);
            h[1] = __uint_as_float(hv.w & 0xffff0000u);
            a67 += e2 * h;
            dsum += ex;
        }
        if (e < oe) {
            const int m = oe - e;                    // 1..7
            const uint32_t rv = srt[e + (g < m ? g : m - 1)];
            const float sjv = s_j[rv >> 8];
            const uint32_t off = ((rv & 0xFFFFFF00u) >> 1) + loff;
            const uint4 hv = *(const uint4*)(hbB + off);
            const float t  = si + sjv;
            const float ex = (g < m) ? __expf(fmaxf(t, NEG_SLOPE * t)) : 0.f;
            const f32x2 e2 = {ex, ex};
            f32x2 h;
            h[0] = __uint_as_float(hv.x << 16);
            h[1] = __uint_as_float(hv.x & 0xffff0000u);
            a01 += e2 * h;
            h[0] = __uint_as_float(hv.y << 16);
            h[1] = __uint_as_float(hv.y & 0xffff0000u);
            a23 += e2 * h;
            h[0] = __uint_as_float(hv.z << 16);
            h[1] = __uint_as_float(hv.z & 0xffff0000u);
            a45 += e2 * h;
            h[0] = __uint_as_float(hv.w << 16);
            h[1] = __uint_as_float(hv.w & 0xffff0000u);
            a67 += e2 * h;
            dsum += ex;
        }

        // cross-group reduction over the 8 edge slots (l8 preserved)
        #pragma unroll
        for (int s = 8; s <= 32; s <<= 1) {
            a01[0] += __shfl_xor(a01[0], s, 64);
            a01[1] += __shfl_xor(a01[1], s, 64);
            a23[0] += __shfl_xor(a23[0], s, 64);
            a23[1] += __shfl_xor(a23[1], s, 64);
            a45[0] += __shfl_xor(a45[0], s, 64);
            a45[1] += __shfl_xor(a45[1], s, 64);
            a67[0] += __shfl_xor(a67[0], s, 64);
            a67[1] += __shfl_xor(a67[1], s, 64);
            dsum   += __shfl_xor(dsum,   s, 64);
        }

        // self loop: row = col = node
        const float t0  = si + s_j[node];
        const float ex0 = __expf(fmaxf(t0, NEG_SLOPE * t0));
        const uint4 hs = *(const uint4*)(hbB + (size_t)node * 128 + loff);
        a01[0] += ex0 * __uint_as_float(hs.x << 16);
        a01[1] += ex0 * __uint_as_float(hs.x & 0xffff0000u);
        a23[0] += ex0 * __uint_as_float(hs.y << 16);
        a23[1] += ex0 * __uint_as_float(hs.y & 0xffff0000u);
        a45[0] += ex0 * __uint_as_float(hs.z << 16);
        a45[1] += ex0 * __uint_as_float(hs.z & 0xffff0000u);
        a67[0] += ex0 * __uint_as_float(hs.w << 16);
        a67[1] += ex0 * __uint_as_float(hs.w & 0xffff0000u);
        dsum += ex0;

        if (g == 0) {
            const float inv = 1.0f / dsum;
            f32x4 o4;
            o4[0] = a01[0] * inv;
            o4[1] = a01[1] * inv;
            o4[2] = a23[0] * inv;
            o4[3] = a23[1] * inv;
            float* op = out + (size_t)node * OUT_C + (l8 << 3);
            __builtin_nontemporal_store(o4, (f32x4*)op);
            o4[0] = a45[0] * inv;
            o4[1] = a45[1] * inv;
            o4[2] = a67[0] * inv;
            o4[3] = a67[1] * inv;
            __builtin_nontemporal_store(o4, (f32x4*)(op + 4));
        }
    }
}

extern "C" void kernel_launch(void* const* d_in, const int* in_sizes, int n_in,
                              void* d_out, int out_size, void* d_ws, size_t ws_size,
                              hipStream_t stream)
{
    const float* x  = (const float*)d_in[0];
    const int*   ei = (const int*)d_in[1];
    const float* W  = (const float*)d_in[2];
    const float* a  = (const float*)d_in[3];

    const int N  = in_sizes[0] / IN_C;     // 100000
    const int E  = in_sizes[1] / 2;        // 3200000
    const int NB = (N + BKT2 - 1) / BKT2;  // 391

    float* out = (float*)d_out;

    // workspace carve-up (~29 MB)
    char* ws = (char*)d_ws;
    ushort* hb      = (ushort*)ws;                ws += (size_t)N * OUT_C * 2;  // 12.8 MB
    float*  s_i     = (float*)ws;                 ws += (size_t)N * 4;
    float*  s_j     = (float*)ws;                 ws += (size_t)N * 4;
    int*    cursor  = (int*)ws;                   ws += (size_t)MAXB * 4;
    ws = (char*)(((uintptr_t)ws + 15) & ~(uintptr_t)15);
    ushort* wfrag   = (ushort*)ws;                ws += 32 * 64 * 8 * 2;        // 32 KB
    ws = (char*)(((uintptr_t)ws + 15) & ~(uintptr_t)15);
    uint32_t* rec   = (uint32_t*)ws;              // NB * CAP * 4 B = 15.2 MB

    // 1. W fragment conversion + cursor init, then projection (MFMA)
    hipLaunchKernelGGL(wconv_kernel, dim3(65), dim3(256), 0, stream,
                       W, wfrag, cursor, NB);
    hipLaunchKernelGGL(fused_h_mfma, dim3((N + 63) / 64), dim3(256), 0, stream,
                       x, wfrag, a, hb, s_i, s_j, N);

    // 2. partition into fixed-capacity coarse buckets (4 B records)
    const int pblocks = (E + PCHUNK - 1) / PCHUNK;
    hipLaunchKernelGGL(partition_kernel, dim3(pblocks), dim3(512), 0, stream,
                       ei, cursor, rec, E, NB);

    // 3. fused per-bucket LDS sort + gather-aggregate (refine deleted)
    hipLaunchKernelGGL(sortgather_kernel, dim3(NB), dim3(1024), 0, stream,
                       rec, hb, s_i, s_j, cursor, out, N);
}